// Round 7
// baseline (307.250 us; speedup 1.0000x reference)
//
#include <hip/hip_runtime.h>

#define T_STEPS 256
#define BATCH   128
#define DIM     1024
#define NROWS   (T_STEPS * BATCH)        // 32768 qx rows

typedef float vfloat4 __attribute__((ext_vector_type(4)));  // nontemporal builtins

// ws float-offset layout (flags zeroed by k_prep each launch; rest written
// before read)
#define WS_M     0                        // float[4*1024]   M = Wq@Wi
#define WS_VP    4096                     // float[64*8]     per-block {sv0..3, sc0..3}
#define WS_FLAG  4608                     // unsigned[128]   sibling-pair flags
#define WS_QX    8192                     // float4[128*256] qx handoff (b*256 + t)

// ---------- prep: atomic-free (proven). blocks 0..15: M by ownership;
//            blocks 16..79: Wh rowsum/cb partials -> vpart ----------
__global__ __launch_bounds__(256) void k_prep(const float* __restrict__ Wi,
                                              const float* __restrict__ Wh,
                                              const float* __restrict__ bi,
                                              const float* __restrict__ bh,
                                              const float* __restrict__ Wq,
                                              float* __restrict__ ws) {
    float*    M     = ws + WS_M;
    float*    vpart = ws + WS_VP;
    unsigned* flag  = (unsigned*)(ws + WS_FLAG);

    int blk  = blockIdx.x;
    int tid  = threadIdx.x;
    int wave = tid >> 6;
    int lane = tid & 63;

    if (blk < 16) {
        // pair flags are re-poisoned by the harness each iteration; re-zero
        // here (k_prep is stream-ordered before k_main)
        if (blk == 0 && tid < BATCH) flag[tid] = 0u;

        // M[w][d] = sum_j Wq[w][j] * Wi[j][d]; block owns d in [blk*64, +64),
        // wave w owns output row w. Wq loads are wave-uniform -> scalar.
        int d = blk * 64 + lane;
        const float* wq = Wq + wave * DIM;
        float acc = 0.f;
        for (int j = 0; j < DIM; j += 8) {
            #pragma unroll
            for (int u = 0; u < 8; u++)
                acc += wq[j + u] * Wi[(size_t)(j + u) * DIM + d];
        }
        M[wave * DIM + d] = acc;
    } else {
        // Wh rowsums + bias terms; each wave handles 4 rows, partials via LDS.
        int bb = blk - 16;                    // 0..63
        __shared__ float red[4][8];
        int j0 = bb * 16 + wave * 4;
        float sv0 = 0.f, sv1 = 0.f, sv2 = 0.f, sv3 = 0.f;
        float sc0 = 0.f, sc1 = 0.f, sc2 = 0.f, sc3 = 0.f;
        #pragma unroll
        for (int jj = 0; jj < 4; jj++) {
            int j = j0 + jj;
            const float4* row = (const float4*)(Wh + (size_t)j * DIM);
            float s = 0.f;
            #pragma unroll
            for (int k = 0; k < 4; k++) {
                float4 t4 = row[k * 64 + lane];
                s += t4.x + t4.y + t4.z + t4.w;
            }
            #pragma unroll
            for (int off = 32; off; off >>= 1) s += __shfl_xor(s, off, 64);
            float bbias = bi[j] + bh[j];
            float q0 = Wq[0 * DIM + j], q1 = Wq[1 * DIM + j];
            float q2 = Wq[2 * DIM + j], q3 = Wq[3 * DIM + j];
            sv0 += q0 * s;  sc0 += q0 * bbias;
            sv1 += q1 * s;  sc1 += q1 * bbias;
            sv2 += q2 * s;  sc2 += q2 * bbias;
            sv3 += q3 * s;  sc3 += q3 * bbias;
        }
        if (lane == 0) {
            red[wave][0] = sv0; red[wave][1] = sv1; red[wave][2] = sv2; red[wave][3] = sv3;
            red[wave][4] = sc0; red[wave][5] = sc1; red[wave][6] = sc2; red[wave][7] = sc3;
        }
        __syncthreads();
        if (tid < 8)
            vpart[bb * 8 + tid] = red[0][tid] + red[1][tid] + red[2][tid] + red[3][tid];
    }
}

// ---------------- recurrence math ----------------
__device__ __forceinline__ float fast_tanh(float x) {
    float e = __expf(2.f * x);
    return (e - 1.f) * __builtin_amdgcn_rcpf(e + 1.f);
}

__device__ __forceinline__ void rec_step(float4 qv,
                                         float b0, float b1, float b2, float b3,
                                         float v0, float v1, float v2, float v3,
                                         float& h, float& c) {
    float z0 = __cosf(qv.x + b0 + h * v0);
    float z1 = __cosf(qv.y + b1 + h * v1);
    float z2 = __cosf(qv.z + b2 + h * v2);
    float z3 = __cosf(qv.w + b3 + h * v3);
    float e1 = z0 * z1;
    float e2 = e1 * z2;
    float e3 = e2 * z3;
    float e0 = z1 * z2 * z3;
    float x0 = __expf(e0), x1 = __expf(e1), x2 = __expf(e2), x3 = __expf(e3);
    float inv = __builtin_amdgcn_rcpf(x0 + x1 + x2 + x3);
    float f  = x0 * inv;
    float i_ = x1 * inv;
    float g  = x2 * inv;
    float o  = x3 * inv;
    c = f * c + i_ * fast_tanh(g);
    h = o * fast_tanh(c);
}

// ---------- main: sibling pair (2b, 2b+1) owns chain b; 256 blocks = 1/CU ----------
// Parity s computes qx rows with t%2==s (full-chip read BW), publishes its
// 2 KB half via uncached agent stores (R4-proven path), swaps with sibling,
// then BOTH blocks run the chain redundantly; each emits only its parity's
// output rows (even/odd interleave -> both write concurrently: full-chip
// write BW). s=0 writes the hx tail row, s=1 the cx tail row.
__global__ __launch_bounds__(512) void k_main(const float* __restrict__ x,
                                              const float* __restrict__ bq,
                                              const float* __restrict__ theta,
                                              float* __restrict__ ws,
                                              float* __restrict__ out)
{
    __shared__ float4 qrow[T_STEPS];              // 4 KB
    const float*  M    = ws + WS_M;
    const float4* vp4  = (const float4*)(ws + WS_VP);
    unsigned*     flag = (unsigned*)(ws + WS_FLAG);
    float*        qxg  = ws + WS_QX;              // handoff region

    const int b    = blockIdx.x >> 1;             // chain 0..127
    const int s    = blockIdx.x & 1;              // parity
    const int tid  = threadIdx.x;
    const int wave = tid >> 6;                    // 0..7
    const int lane = tid & 63;

    // ---- phase A: qx rows with t%2==s -> LDS (8 waves x 16 rows) ----
    {
        float4 m[4][4];                           // M fragment in regs
        #pragma unroll
        for (int w = 0; w < 4; w++)
            #pragma unroll
            for (int k = 0; k < 4; k++)
                m[w][k] = *(const float4*)(M + w * DIM + k * 256 + lane * 4);

        #pragma unroll 2
        for (int j = 0; j < 16; ++j) {
            int t = s + 2 * (wave + 8 * j);       // this block's parity rows
            const float4* row = (const float4*)(x + ((size_t)t * BATCH + b) * DIM);
            float a0 = 0.f, a1 = 0.f, a2 = 0.f, a3 = 0.f;
            #pragma unroll
            for (int k = 0; k < 4; k++) {
                float4 xv = row[k * 64 + lane];   // contiguous 1 KB/instr
                a0 += xv.x * m[0][k].x + xv.y * m[0][k].y + xv.z * m[0][k].z + xv.w * m[0][k].w;
                a1 += xv.x * m[1][k].x + xv.y * m[1][k].y + xv.z * m[1][k].z + xv.w * m[1][k].w;
                a2 += xv.x * m[2][k].x + xv.y * m[2][k].y + xv.z * m[2][k].z + xv.w * m[2][k].w;
                a3 += xv.x * m[3][k].x + xv.y * m[3][k].y + xv.z * m[3][k].z + xv.w * m[3][k].w;
            }
            #pragma unroll
            for (int off = 32; off; off >>= 1) {
                a0 += __shfl_xor(a0, off, 64);
                a1 += __shfl_xor(a1, off, 64);
                a2 += __shfl_xor(a2, off, 64);
                a3 += __shfl_xor(a3, off, 64);
            }
            if (lane == 0) qrow[t] = make_float4(a0, a1, a2, a3);
        }
    }
    __syncthreads();

    // ---- publish own half: 256 x 8B uncached agent stores ----
    if (tid < 256) {
        int t    = s + 2 * (tid >> 1);
        int half = tid & 1;
        float2 d = ((const float2*)qrow)[t * 2 + half];
        unsigned long long u = ((unsigned long long)__float_as_uint(d.y) << 32)
                             |  (unsigned long long)__float_as_uint(d.x);
        __hip_atomic_store(
            (unsigned long long*)(qxg + ((size_t)b * 256 + t) * 4 + half * 2),
            u, __ATOMIC_RELAXED, __HIP_MEMORY_SCOPE_AGENT);
    }
    __syncthreads();                              // drains vmcnt: stores visible
    if (tid == 0) {
        __hip_atomic_fetch_add(&flag[b], 1u, __ATOMIC_RELAXED, __HIP_MEMORY_SCOPE_AGENT);
        for (int k = 0; k < (1 << 20); ++k) {     // bounded: bug -> wrong, not hang
            if (__hip_atomic_load(&flag[b], __ATOMIC_RELAXED, __HIP_MEMORY_SCOPE_AGENT) >= 2u)
                break;
            __builtin_amdgcn_s_sleep(2);
        }
    }
    __syncthreads();

    // ---- consume sibling half: 256 x 8B uncached agent loads -> LDS ----
    if (tid < 256) {
        int t    = (s ^ 1) + 2 * (tid >> 1);
        int half = tid & 1;
        unsigned long long u = __hip_atomic_load(
            (const unsigned long long*)(qxg + ((size_t)b * 256 + t) * 4 + half * 2),
            __ATOMIC_RELAXED, __HIP_MEMORY_SCOPE_AGENT);
        ((float2*)qrow)[t * 2 + half] =
            make_float2(__uint_as_float((unsigned)u),
                        __uint_as_float((unsigned)(u >> 32)));
    }
    __syncthreads();
    if (wave >= 4) return;                        // 4 waves carry phase B

    // ---- v/cb constants: reduce 64 vpart blocks lane-parallel ----
    float4 sa = vp4[lane * 2];                    // {sv0..3}
    float4 sc = vp4[lane * 2 + 1];                // {sc0..3}
    #pragma unroll
    for (int off = 32; off; off >>= 1) {
        sa.x += __shfl_xor(sa.x, off, 64);  sa.y += __shfl_xor(sa.y, off, 64);
        sa.z += __shfl_xor(sa.z, off, 64);  sa.w += __shfl_xor(sa.w, off, 64);
        sc.x += __shfl_xor(sc.x, off, 64);  sc.y += __shfl_xor(sc.y, off, 64);
        sc.z += __shfl_xor(sc.z, off, 64);  sc.w += __shfl_xor(sc.w, off, 64);
    }
    const float v0 = sa.x, v1 = sa.y, v2 = sa.z, v3 = sa.w;
    const float b0 = sc.x + bq[0] + theta[0];
    const float b1 = sc.y + bq[1] + theta[1];
    const float b2 = sc.z + bq[2] + theta[2];
    const float b3 = sc.w + bq[3] + theta[3];

    float h = 0.f, c = 0.f;

    // parity filter: t steps by 8 so (tt)&1 is compile-time; s is uniform
    #define EMIT_H(tt)                                                           \
        do {                                                                     \
            if ((((tt) & 1)) == s) {                                             \
                vfloat4 vv = {h, h, h, h};                                       \
                __builtin_nontemporal_store(vv,                                  \
                    (vfloat4*)(out + ((size_t)(tt) * BATCH + b) * DIM            \
                               + wave * 256) + lane);                            \
            }                                                                    \
        } while (0)

    // rolling 8-deep prefetch from LDS (broadcast reads)
    float4 q0 = qrow[0], q1 = qrow[1], q2 = qrow[2], q3 = qrow[3];
    float4 q4 = qrow[4], q5 = qrow[5], q6 = qrow[6], q7 = qrow[7];

    for (int t = 0; t < T_STEPS; t += 8) {
        float4 n0, n1, n2, n3, n4, n5, n6, n7;
        if (t + 8 < T_STEPS) {
            n0 = qrow[t + 8];  n1 = qrow[t + 9];
            n2 = qrow[t + 10]; n3 = qrow[t + 11];
            n4 = qrow[t + 12]; n5 = qrow[t + 13];
            n6 = qrow[t + 14]; n7 = qrow[t + 15];
        }
        rec_step(q0, b0, b1, b2, b3, v0, v1, v2, v3, h, c); EMIT_H(t + 0);
        rec_step(q1, b0, b1, b2, b3, v0, v1, v2, v3, h, c); EMIT_H(t + 1);
        rec_step(q2, b0, b1, b2, b3, v0, v1, v2, v3, h, c); EMIT_H(t + 2);
        rec_step(q3, b0, b1, b2, b3, v0, v1, v2, v3, h, c); EMIT_H(t + 3);
        rec_step(q4, b0, b1, b2, b3, v0, v1, v2, v3, h, c); EMIT_H(t + 4);
        rec_step(q5, b0, b1, b2, b3, v0, v1, v2, v3, h, c); EMIT_H(t + 5);
        rec_step(q6, b0, b1, b2, b3, v0, v1, v2, v3, h, c); EMIT_H(t + 6);
        rec_step(q7, b0, b1, b2, b3, v0, v1, v2, v3, h, c); EMIT_H(t + 7);
        q0 = n0; q1 = n1; q2 = n2; q3 = n3; q4 = n4; q5 = n5; q6 = n6; q7 = n7;
    }
    #undef EMIT_H

    // tail rows: s=0 -> hx broadcast (final h); s=1 -> cx broadcast (final c)
    if (s == 0) {
        vfloat4 hv = {h, h, h, h};
        __builtin_nontemporal_store(hv,
            (vfloat4*)(out + ((size_t)NROWS + b) * DIM + wave * 256) + lane);
    } else {
        vfloat4 cv = {c, c, c, c};
        __builtin_nontemporal_store(cv,
            (vfloat4*)(out + ((size_t)NROWS + BATCH + b) * DIM + wave * 256) + lane);
    }
}

extern "C" void kernel_launch(void* const* d_in, const int* in_sizes, int n_in,
                              void* d_out, int out_size, void* d_ws, size_t ws_size,
                              hipStream_t stream) {
    const float* inputs = (const float*)d_in[0];
    const float* Wi     = (const float*)d_in[1];
    const float* bi     = (const float*)d_in[2];
    const float* Wh     = (const float*)d_in[3];
    const float* bh     = (const float*)d_in[4];
    const float* Wq     = (const float*)d_in[5];
    const float* bq     = (const float*)d_in[6];
    const float* theta  = (const float*)d_in[7];
    float* out = (float*)d_out;
    float* ws  = (float*)d_ws;

    k_prep<<<80,  256, 0, stream>>>(Wi, Wh, bi, bh, Wq, ws);
    k_main<<<256, 512, 0, stream>>>(inputs, bq, theta, ws, out);
}